// Round 7
// baseline (6508.374 us; speedup 1.0000x reference)
//
#include <hip/hip_runtime.h>

typedef unsigned short u16;
typedef unsigned long long u64;
typedef short bf16x8 __attribute__((ext_vector_type(8)));
typedef float f32x4 __attribute__((ext_vector_type(4)));

#define B_ 256
#define T_ 512
#define I_ 64
#define H_ 512
#define RING 16

// ---------------- ws layout (bytes) ----------------
// Tagged exchange: cell = u64 [lo32 = 2 bf16 | hi32 = step tag]. Layout
// [k8 = k/8][row 0..255][4 cells] -> consumer lane loads 4 consecutive u64 (32B),
// tag check == step. No data/flag ordering problem (tag travels inside the atom).
// Only fC (ring back-pressure) mailbox remains: [8 groups][32 lines][32 slots] u32.
#define OFF_FC    0u           // 8192 u32 = 32 KB
#define OFF_B0    32768u       // 2048 f32
#define OFF_B1    40960u       // 2048 f32
#define OFF_WIH0  49152u       // 2048x64 bf16
#define OFF_WHH0  311296u      // 2048x512 bf16
#define OFF_WIH1  2408448u     // 2048x512 bf16
#define OFF_WHH1  4505600u     // 2048x512 bf16
#define OFF_HX0   6602752u     // 2 x 65536 u64 = 1 MB (L0 exchange, tagged)
#define OFF_HX1   7651328u     // 1 MB (L1 exchange, tagged)
#define OFF_RING  8699904u     // RING x 65536 u64 = 8 MB (h1 ring, tagged)
#define WS_NEEDED 17088512u

#define AQ __ATOMIC_RELAXED
#define SC __HIP_MEMORY_SCOPE_AGENT

static __device__ __forceinline__ u16 f2b(float f) {
  union { float f; unsigned u; } v; v.f = f;
  unsigned r = (v.u + 0x7FFFu + ((v.u >> 16) & 1u)) >> 16;
  return (u16)r;
}
static __device__ __forceinline__ float sigm(float x) { return 1.f / (1.f + __expf(-x)); }
static __device__ __forceinline__ float tanh_(float x) { return 1.f - 2.f / (__expf(2.f * x) + 1.f); }

// ---- tagged-sweep helpers: 8 A-frags (r 0..3 x mt 0..1) of 4 u64 cells each ----
static __device__ __forceinline__ void sweep_ptrs(const u64* base, int wv, int quad, int l15,
                                                  int ib, const u64** fp) {
#pragma unroll
  for (int r = 0; r < 4; ++r)
#pragma unroll
    for (int mt = 0; mt < 2; ++mt)
      fp[r * 2 + mt] = base +
        ((size_t)((wv * 16 + r * 4 + quad) * 256 + ib * 32 + mt * 16 + l15)) * 4;
}
static __device__ __forceinline__ void sweep_issue(const u64** fp, u64 (*raw)[4]) {
#pragma unroll
  for (int f = 0; f < 8; ++f)
#pragma unroll
    for (int c = 0; c < 4; ++c)
      raw[f][c] = __hip_atomic_load(fp[f] + c, AQ, SC);
}
static __device__ __forceinline__ void sweep_finish(const u64** fp, u64 (*raw)[4],
                                                    unsigned tag, bf16x8 (*af)[2]) {
  unsigned pend = 0xFFu;
  while (pend) {
    unsigned np = 0;
#pragma unroll
    for (int f = 0; f < 8; ++f)
      if (pend & (1u << f)) {
        bool ok = (unsigned)(raw[f][0] >> 32) == tag && (unsigned)(raw[f][1] >> 32) == tag &&
                  (unsigned)(raw[f][2] >> 32) == tag && (unsigned)(raw[f][3] >> 32) == tag;
        if (!ok) {
          np |= 1u << f;
#pragma unroll
          for (int c = 0; c < 4; ++c) raw[f][c] = __hip_atomic_load(fp[f] + c, AQ, SC);
        }
      }
    pend = np;
  }
#pragma unroll
  for (int f = 0; f < 8; ++f) {
    union { unsigned w[4]; bf16x8 v; } u;
#pragma unroll
    for (int c = 0; c < 4; ++c) u.w[c] = (unsigned)raw[f][c];
    af[f >> 1][f & 1] = u.v;
  }
}

// ---------------- prep: bf16 weights, bias sums, fC zero, out=bfc ----------------
__global__ void prep_kernel(const float* __restrict__ Wih0, const float* __restrict__ Whh0,
                            const float* __restrict__ bih0, const float* __restrict__ bhh0,
                            const float* __restrict__ Wih1, const float* __restrict__ Whh1,
                            const float* __restrict__ bih1, const float* __restrict__ bhh1,
                            const float* __restrict__ bfc, float* __restrict__ out,
                            char* __restrict__ ws) {
  unsigned* fC = (unsigned*)(ws + OFF_FC);
  float* b0 = (float*)(ws + OFF_B0);
  float* b1 = (float*)(ws + OFF_B1);
  u16* wih0b = (u16*)(ws + OFF_WIH0);
  u16* whh0b = (u16*)(ws + OFF_WHH0);
  u16* wih1b = (u16*)(ws + OFF_WIH1);
  u16* whh1b = (u16*)(ws + OFF_WHH1);

  long long i = (long long)blockIdx.x * 256 + threadIdx.x;
  if (i < 8192) { __hip_atomic_store(&fC[i], 0u, AQ, SC); return; }
  i -= 8192;
  if (i < 256) { out[i] = bfc[0]; return; }   // FC bias; L1 atomicAdds partials
  i -= 256;
  if (i < 2048) { b0[i] = bih0[i] + bhh0[i]; return; }
  i -= 2048;
  if (i < 2048) { b1[i] = bih1[i] + bhh1[i]; return; }
  i -= 2048;
  if (i < 131072) { wih0b[i] = f2b(Wih0[i]); return; }
  i -= 131072;
  if (i < 1048576) { whh0b[i] = f2b(Whh0[i]); return; }
  i -= 1048576;
  if (i < 1048576) { wih1b[i] = f2b(Wih1[i]); return; }
  i -= 1048576;
  if (i < 1048576) { whh1b[i] = f2b(Whh1[i]); return; }
}

// ---------------- fused 2-layer pipelined LSTM, tagged exchange ----------------
// 512 blocks co-resident (2/CU): 0-255 = L0, 256-511 = L1 (lag 1). Per layer:
// jn = bx&31 (16 h-cols), ib = bx>>5 (32 batch rows); 4 waves K-split; Whh in VGPRs.
template <bool IS_L0>
__device__ __forceinline__ void lstm_body(
    int bx,
    const float* __restrict__ x,      // L0: [B,T,64]
    const u16* __restrict__ Wib,      // bf16: L0 [2048][64], L1 [2048][512]
    const u16* __restrict__ Whb,      // bf16 [2048][512]
    const float* __restrict__ bias,   // [2048]
    u64* __restrict__ hxq,            // own tagged exchange [2][65536]
    u64* __restrict__ ringq,          // tagged ring [RING][65536]
    const float* __restrict__ Wfc, float* __restrict__ out,
    unsigned* __restrict__ fC,        // ring back-pressure mailbox
    float* __restrict__ Gp_s, u16* __restrict__ Ax_s)
{
  const int tid = threadIdx.x;
  const int wv = tid >> 6;
  const int lane = tid & 63;
  const int quad = lane >> 4;
  const int l15 = lane & 15;
  const int jn = bx & 31;
  const int ib = bx >> 5;

  // ---- Whh B-frags resident in VGPRs (wave owns ksteps wv*4..wv*4+3)
  bf16x8 Bh[4][4];
#pragma unroll
  for (int r = 0; r < 4; ++r)
#pragma unroll
    for (int nt = 0; nt < 4; ++nt)
      Bh[r][nt] = *(const bf16x8*)&Whb[(size_t)(nt * 512 + jn * 16 + l15) * 512 +
                                       (wv * 4 + r) * 32 + quad * 8];
  bf16x8 Bx0[4];  // L0 input weights (waves 0,1; kstep = wv)
  if constexpr (IS_L0) {
    if (wv < 2) {
#pragma unroll
      for (int nt = 0; nt < 4; ++nt)
        Bx0[nt] = *(const bf16x8*)&Wib[(size_t)(nt * 512 + jn * 16 + l15) * 64 +
                                       wv * 32 + quad * 8];
    }
  }

  const int erow = tid >> 3;     // elementwise: batch row 0..31
  const int ecp = tid & 7;       // col pair
  float bias2[4][2];
#pragma unroll
  for (int g = 0; g < 4; ++g) {
    bias2[g][0] = bias[g * 512 + jn * 16 + 2 * ecp];
    bias2[g][1] = bias[g * 512 + jn * 16 + 2 * ecp + 1];
  }
  float cst2[2] = {0.f, 0.f};
  const f32x4 zf = {0.f, 0.f, 0.f, 0.f};
  const unsigned lineoff = ((unsigned)ib * 32 + jn) * 32;
  const int bg = ib * 32 + erow;
  const int hg = jn * 16 + 2 * ecp;
  // tagged-cell u64 index for this thread's (bg, hg) pair
  const unsigned soff = (unsigned)(((hg >> 3) * 256 + bg) * 4 + (ecp & 3));

  if constexpr (IS_L0) {  // prologue: stage x(0)
    int row = tid >> 3, cc = (tid & 7) * 8;
    const float* xp = x + ((size_t)(ib * 32 + row) * T_) * 64 + cc;
    float4 a = *(const float4*)xp;
    float4 b = *(const float4*)(xp + 4);
    uint4 v;
    v.x = (unsigned)f2b(a.x) | ((unsigned)f2b(a.y) << 16);
    v.y = (unsigned)f2b(a.z) | ((unsigned)f2b(a.w) << 16);
    v.z = (unsigned)f2b(b.x) | ((unsigned)f2b(b.y) << 16);
    v.w = (unsigned)f2b(b.z) | ((unsigned)f2b(b.w) << 16);
    *(uint4*)&Ax_s[row * 72 + cc] = v;
    __syncthreads();
  }

  for (int t = 0; t < T_; ++t) {
    f32x4 acc[2][4];
#pragma unroll
    for (int mt = 0; mt < 2; ++mt)
#pragma unroll
      for (int nt = 0; nt < 4; ++nt) acc[mt][nt] = zf;

    const u64* fp[8];
    u64 raw[8][4];
    bf16x8 af[4][2];

    if constexpr (IS_L0) {
      // issue recurrent sweep early (overlap MALL latency with input GEMM)
      if (t) {
        sweep_ptrs(hxq + (size_t)(t & 1) * 65536, wv, quad, l15, ib, fp);
        sweep_issue(fp, raw);
      }
      // input GEMM from Ax_s (staged prev step)
      if (wv < 2) {
        int kk = wv * 32 + quad * 8;
        bf16x8 a0 = *(const bf16x8*)&Ax_s[l15 * 72 + kk];
        bf16x8 a1 = *(const bf16x8*)&Ax_s[(16 + l15) * 72 + kk];
#pragma unroll
        for (int nt = 0; nt < 4; ++nt) {
          acc[0][nt] = __builtin_amdgcn_mfma_f32_16x16x32_bf16(a0, Bx0[nt], acc[0][nt], 0, 0, 0);
          acc[1][nt] = __builtin_amdgcn_mfma_f32_16x16x32_bf16(a1, Bx0[nt], acc[1][nt], 0, 0, 0);
        }
      }
      if (t) {
        sweep_finish(fp, raw, (unsigned)t, af);
#pragma unroll
        for (int r = 0; r < 4; ++r)
#pragma unroll
          for (int mt = 0; mt < 2; ++mt)
#pragma unroll
            for (int nt = 0; nt < 4; ++nt)
              acc[mt][nt] = __builtin_amdgcn_mfma_f32_16x16x32_bf16(af[r][mt], Bh[r][nt],
                                                                    acc[mt][nt], 0, 0, 0);
      }
      // ring back-pressure check (rarely blocks; before syncA, store after)
      if (t >= RING) {
        unsigned tgt = (unsigned)(t - (RING - 1));
        for (;;) {
          unsigned v = (lane < 32) ? __hip_atomic_load(&fC[lineoff + lane], AQ, SC) : 0xFFFFFFFFu;
          if (!__any(v < tgt)) break;
        }
      }
    } else {
      // L1: ring sweep (h1(t)), then hx sweep overlapped with ring MFMA
      sweep_ptrs(ringq + (size_t)(t & (RING - 1)) * 65536, wv, quad, l15, ib, fp);
      sweep_issue(fp, raw);
      sweep_finish(fp, raw, (unsigned)t, af);   // af = ring A-frags
      bf16x8 afr[4][2];
#pragma unroll
      for (int r = 0; r < 4; ++r)
#pragma unroll
        for (int mt = 0; mt < 2; ++mt) afr[r][mt] = af[r][mt];
      if (t) {  // issue recurrent sweep now, overlap with input MFMA
        sweep_ptrs(hxq + (size_t)(t & 1) * 65536, wv, quad, l15, ib, fp);
        sweep_issue(fp, raw);
      }
      // input GEMM: Bx from global (L2-hot weights)
#pragma unroll
      for (int r = 0; r < 4; ++r) {
        bf16x8 bx[4];
#pragma unroll
        for (int nt = 0; nt < 4; ++nt)
          bx[nt] = *(const bf16x8*)&Wib[(size_t)(nt * 512 + jn * 16 + l15) * 512 +
                                        (wv * 4 + r) * 32 + quad * 8];
#pragma unroll
        for (int nt = 0; nt < 4; ++nt) {
          acc[0][nt] = __builtin_amdgcn_mfma_f32_16x16x32_bf16(afr[r][0], bx[nt], acc[0][nt], 0, 0, 0);
          acc[1][nt] = __builtin_amdgcn_mfma_f32_16x16x32_bf16(afr[r][1], bx[nt], acc[1][nt], 0, 0, 0);
        }
      }
      if (t) {
        sweep_finish(fp, raw, (unsigned)t, af);
#pragma unroll
        for (int r = 0; r < 4; ++r)
#pragma unroll
          for (int mt = 0; mt < 2; ++mt)
#pragma unroll
            for (int nt = 0; nt < 4; ++nt)
              acc[mt][nt] = __builtin_amdgcn_mfma_f32_16x16x32_bf16(af[r][mt], Bh[r][nt],
                                                                    acc[mt][nt], 0, 0, 0);
      }
    }

    // ---- dump per-wave partials (D: col=l15, row=quad*4+reg)
#pragma unroll
    for (int mt = 0; mt < 2; ++mt)
#pragma unroll
      for (int nt = 0; nt < 4; ++nt)
#pragma unroll
        for (int rr = 0; rr < 4; ++rr)
          Gp_s[(wv * 32 + mt * 16 + quad * 4 + rr) * 68 + nt * 16 + l15] = acc[mt][nt][rr];
    __syncthreads();  // A

    // ---- reduce partials, gates, c/h update, tagged stores
    {
      float pre[4][2];
#pragma unroll
      for (int g = 0; g < 4; ++g) {
        int c = g * 16 + 2 * ecp;
        float s0 = bias2[g][0], s1 = bias2[g][1];
#pragma unroll
        for (int w = 0; w < 4; ++w) {
          s0 += Gp_s[(w * 32 + erow) * 68 + c];
          s1 += Gp_s[(w * 32 + erow) * 68 + c + 1];
        }
        pre[g][0] = s0; pre[g][1] = s1;
      }
      float hv[2];
#pragma unroll
      for (int j = 0; j < 2; ++j) {
        float iv = sigm(pre[0][j]);
        float fv = sigm(pre[1][j]);
        float gv = tanh_(pre[2][j]);
        float ov = sigm(pre[3][j]);
        float cn = fv * cst2[j] + iv * gv;
        cst2[j] = cn;
        hv[j] = ov * tanh_(cn);
      }
      u64 pack = (u64)((unsigned)f2b(hv[0]) | ((unsigned)f2b(hv[1]) << 16));
      __hip_atomic_store(&hxq[(size_t)((t + 1) & 1) * 65536 + soff],
                         pack | ((u64)(unsigned)(t + 1) << 32), AQ, SC);
      if constexpr (IS_L0) {
        __hip_atomic_store(&ringq[(size_t)(t & (RING - 1)) * 65536 + soff],
                           pack | ((u64)(unsigned)t << 32), AQ, SC);
      } else if (t == T_ - 1) {
        float part = hv[0] * Wfc[hg] + hv[1] * Wfc[hg + 1];
        part += __shfl_down(part, 4, 8);
        part += __shfl_down(part, 2, 8);
        part += __shfl_down(part, 1, 8);
        if (ecp == 0) atomicAdd(&out[bg], part);
      }
    }

    if constexpr (IS_L0) {
      // stage x(t+1) (after syncA: phase-1 readers of step t are done)
      if (t + 1 < T_) {
        int row = tid >> 3, cc = (tid & 7) * 8;
        const float* xp = x + ((size_t)(ib * 32 + row) * T_ + t + 1) * 64 + cc;
        float4 a = *(const float4*)xp;
        float4 b = *(const float4*)(xp + 4);
        uint4 v;
        v.x = (unsigned)f2b(a.x) | ((unsigned)f2b(a.y) << 16);
        v.y = (unsigned)f2b(a.z) | ((unsigned)f2b(a.w) << 16);
        v.z = (unsigned)f2b(b.x) | ((unsigned)f2b(b.y) << 16);
        v.w = (unsigned)f2b(b.z) | ((unsigned)f2b(b.w) << 16);
        *(uint4*)&Ax_s[row * 72 + cc] = v;
      }
    } else {
      // publish ring consumption (ring reads of step t retired before syncA)
      if (wv == 0 && lane < 32)
        __hip_atomic_store(&fC[((unsigned)ib * 32 + lane) * 32 + jn],
                           (unsigned)(t + 1), AQ, SC);
    }
    __syncthreads();  // B (protects Gp_s reuse + Ax_s staging)
  }
}

__global__ __launch_bounds__(256, 2) void lstm_fused(
    const float* __restrict__ x,
    const u16* __restrict__ wih0, const u16* __restrict__ whh0, const float* __restrict__ b0,
    const u16* __restrict__ wih1, const u16* __restrict__ whh1, const float* __restrict__ b1,
    u64* __restrict__ hx0, u64* __restrict__ hx1, u64* __restrict__ ringq,
    const float* __restrict__ Wfc, float* __restrict__ out, unsigned* __restrict__ fC)
{
  __shared__ __align__(16) float Gp_s[4 * 32 * 68];
  __shared__ __align__(16) u16 Ax_s[32 * 72];
  if (blockIdx.x < 256)
    lstm_body<true>(blockIdx.x, x, wih0, whh0, b0, hx0, ringq,
                    (const float*)nullptr, (float*)nullptr, fC, Gp_s, Ax_s);
  else
    lstm_body<false>(blockIdx.x - 256, (const float*)nullptr, wih1, whh1, b1, hx1, ringq,
                     Wfc, out, fC, Gp_s, Ax_s);
}

extern "C" void kernel_launch(void* const* d_in, const int* in_sizes, int n_in,
                              void* d_out, int out_size, void* d_ws, size_t ws_size,
                              hipStream_t stream) {
  if (ws_size < (size_t)WS_NEEDED) return;

  const float* x    = (const float*)d_in[0];
  const float* Wih0 = (const float*)d_in[1];
  const float* Whh0 = (const float*)d_in[2];
  const float* bih0 = (const float*)d_in[3];
  const float* bhh0 = (const float*)d_in[4];
  const float* Wih1 = (const float*)d_in[5];
  const float* Whh1 = (const float*)d_in[6];
  const float* bih1 = (const float*)d_in[7];
  const float* bhh1 = (const float*)d_in[8];
  const float* Wfc  = (const float*)d_in[9];
  const float* bfc  = (const float*)d_in[10];

  char* ws = (char*)d_ws;
  unsigned* fC   = (unsigned*)(ws + OFF_FC);
  float* b0      = (float*)(ws + OFF_B0);
  float* b1      = (float*)(ws + OFF_B1);
  u16* wih0b     = (u16*)(ws + OFF_WIH0);
  u16* whh0b     = (u16*)(ws + OFF_WHH0);
  u16* wih1b     = (u16*)(ws + OFF_WIH1);
  u16* whh1b     = (u16*)(ws + OFF_WHH1);
  u64* hx0       = (u64*)(ws + OFF_HX0);
  u64* hx1       = (u64*)(ws + OFF_HX1);
  u64* ringq     = (u64*)(ws + OFF_RING);
  float* out     = (float*)d_out;

  // prep: 8192 + 256 + 2048*2 + 131072 + 3*1048576 = 3,289,344 = 12849 x 256
  prep_kernel<<<12849, 256, 0, stream>>>(Wih0, Whh0, bih0, bhh0, Wih1, Whh1, bih1, bhh1,
                                         bfc, out, ws);

  lstm_fused<<<512, 256, 0, stream>>>(x, wih0b, whh0b, b0, wih1b, whh1b, b1,
                                      hx0, hx1, ringq, Wfc, out, fC);
}